// Round 3
// baseline (111.453 us; speedup 1.0000x reference)
//
#include <hip/hip_runtime.h>
#include <hip/hip_bf16.h>
#include <cstdint>

// Problem constants (fixed by reference)
#define SEQ   2048
#define CH    1024
#define NHEAD 16
#define KSZ   7
#define NCOL  112      // NHEAD * KSZ
#define PADW  3        // KSZ/2

#define NTHREADS 256
#define NKSTEP   32    // CH / 32 (K-steps of the 16x16x32 MFMA)

// Workspace layout
#define WSB_BYTES   (NKSTEP * 7 * 64 * 16)          // 229,376 B bf16 B-frags
#define KBUF_OFF    262144                           // float Kbuf at 256 KiB
#define KBUF_BYTES  (4 * SEQ * NCOL * 4)             // 3,670,016 B
#define WS_NEEDED   (KBUF_OFF + KBUF_BYTES)

// Conv tiling
#define BM2      8     // rows per conv block -> 1024 blocks (4/CU)

typedef __bf16 v8bf __attribute__((ext_vector_type(8)));
typedef float  v4f  __attribute__((ext_vector_type(4)));

// ---------------------------------------------------------------------------
// K1: W_pred fp32 [1024][112] -> bf16 packed in MFMA B-frag order:
// ws[((s*7 + t)*64 + lane)*8 + j] = W[k = s*32 + (lane>>4)*8 + j][n = t*16 + (lane&15)]
// ---------------------------------------------------------------------------
__global__ __launch_bounds__(256)
void prep_w(const float* __restrict__ Wp, __bf16* __restrict__ wsB) {
    const int g  = blockIdx.x * 256 + threadIdx.x;   // 0..114687
    const int j  = g & 7;
    const int l  = (g >> 3) & 63;
    const int st = g >> 9;            // s*7 + t
    const int s  = st / 7;
    const int t  = st - s * 7;
    const int k  = s * 32 + (l >> 4) * 8 + j;
    const int n  = t * 16 + (l & 15);
    wsB[g] = (__bf16)Wp[k * NCOL + n];
}

// ---------------------------------------------------------------------------
// K2: kernels = x @ W + b  -> Kbuf fp32 [B*S][112]
// 512 blocks x 256 threads; block owns 16 seq rows; wave w -> n-tiles {2w,2w+1}
// (wave 3 computes tile 6 once). Barrier-free: A from global (cvt to bf16),
// B-frags as single dwordx4 loads from wsB.
// ---------------------------------------------------------------------------
__global__ __launch_bounds__(NTHREADS)
void gemm_kernels(const float* __restrict__ x,
                  const __bf16* __restrict__ wsB,
                  const float* __restrict__ bp,
                  float* __restrict__ Kbuf)
{
    const int tid  = threadIdx.x;
    const int bb   = blockIdx.x;          // 0..511
    const int b    = bb >> 7;
    const int s0   = (bb & 127) << 4;

    const int wave = tid >> 6;
    const int lane = tid & 63;
    const int lq   = lane >> 4;
    const int lm   = lane & 15;

    const int tile0 = wave * 2;                       // 0,2,4,6
    const int tile1 = (wave < 3) ? wave * 2 + 1 : 6;  // 1,3,5,(dup 6)

    v4f acc0 = (v4f){0.f, 0.f, 0.f, 0.f};
    v4f acc1 = (v4f){0.f, 0.f, 0.f, 0.f};

    // A-frag: lane (lq,lm) covers x[s0+lm][k = s*32 + lq*8 .. +7]
    const float* arow = x + ((size_t)b * SEQ + s0 + lm) * CH + lq * 8;

    #pragma unroll 8
    for (int s = 0; s < NKSTEP; ++s) {
        const float* p = arow + s * 32;
        const v4f v0 = *(const v4f*)p;
        const v4f v1 = *(const v4f*)(p + 4);
        v8bf af;
        af[0] = (__bf16)v0.x; af[1] = (__bf16)v0.y;
        af[2] = (__bf16)v0.z; af[3] = (__bf16)v0.w;
        af[4] = (__bf16)v1.x; af[5] = (__bf16)v1.y;
        af[6] = (__bf16)v1.z; af[7] = (__bf16)v1.w;

        const v8bf bf0 = *(const v8bf*)&wsB[(size_t)((s * 7 + tile0) * 64 + lane) * 8];
        const v8bf bf1 = *(const v8bf*)&wsB[(size_t)((s * 7 + tile1) * 64 + lane) * 8];

        acc0 = __builtin_amdgcn_mfma_f32_16x16x32_bf16(af, bf0, acc0, 0, 0, 0);
        acc1 = __builtin_amdgcn_mfma_f32_16x16x32_bf16(af, bf1, acc1, 0, 0, 0);
    }

    // Epilogue -> global Kbuf. C/D layout: col = lane&15, row = (lane>>4)*4 + reg.
    float* krow = Kbuf + (size_t)(b * SEQ + s0) * NCOL;
    {
        const int ct0 = tile0 * 16 + lm;
        const float bias0 = bp[ct0];
        #pragma unroll
        for (int r = 0; r < 4; ++r)
            krow[(size_t)(lq * 4 + r) * NCOL + ct0] = acc0[r] + bias0;
    }
    if (wave < 3) {
        const int ct1 = tile1 * 16 + lm;
        const float bias1 = bp[ct1];
        #pragma unroll
        for (int r = 0; r < 4; ++r)
            krow[(size_t)(lq * 4 + r) * NCOL + ct1] = acc1[r] + bias1;
    }
}

// ---------------------------------------------------------------------------
// K3: dynamic conv, pure streaming. 1024 blocks; block owns 8 seq rows of one
// batch; thread owns 4 channels (head = tid>>4). Kernels chunk is 3584 B
// CONTIGUOUS in Kbuf -> one coalesced float4 stage to LDS. 14-row register
// window preloaded before the single barrier.
// ---------------------------------------------------------------------------
__global__ __launch_bounds__(NTHREADS)
void dynconv(const float* __restrict__ x,
             const float* __restrict__ Kbuf,
             float* __restrict__ out)
{
    __shared__ float ldsK[BM2 * NCOL];    // 3,584 B

    const int tid = threadIdx.x;
    const int bb  = blockIdx.x;           // 0..1023
    const int b   = bb >> 8;
    const int s0  = (bb & 255) << 3;

    // Stage kernels chunk (896 floats, contiguous): threads 0..223, float4 each.
    const float* kb = Kbuf + (size_t)(b * SEQ + s0) * NCOL;
    if (tid < 224) {
        const v4f kv = *(const v4f*)(kb + tid * 4);
        *(v4f*)(&ldsK[tid * 4]) = kv;
    }

    const int h  = tid >> 4;
    const int c4 = tid << 2;
    const float* xb = x + (size_t)b * SEQ * CH + c4;

    v4f win[BM2 + 6];
    #pragma unroll
    for (int i = 0; i < BM2 + 6; ++i) {
        const int sg = s0 - PADW + i;
        win[i] = (sg >= 0 && sg < SEQ) ? *(const v4f*)(xb + (size_t)sg * CH)
                                       : (v4f){0.f, 0.f, 0.f, 0.f};
    }

    __syncthreads();

    float* ob = out + ((size_t)b * SEQ + s0) * CH + c4;
    #pragma unroll
    for (int r = 0; r < BM2; ++r) {
        const float* kp = &ldsK[r * NCOL + h * KSZ];
        v4f a = (v4f){0.f, 0.f, 0.f, 0.f};
        #pragma unroll
        for (int i = 0; i < KSZ; ++i) {
            a += kp[i] * win[r + i];
        }
        __builtin_nontemporal_store(a, (v4f*)(ob + (size_t)r * CH));
    }
}

// ---------------------------------------------------------------------------
// Fallback (ws too small): round-2 fused kernel, direct strided W loads.
// ---------------------------------------------------------------------------
__global__ __launch_bounds__(NTHREADS, 2)
void dynconv_fused_fb(const float* __restrict__ x,
                      const float* __restrict__ Wp,
                      const float* __restrict__ bp,
                      float* __restrict__ out)
{
    __shared__ float ldsK[16 * 113];
    const int tid  = threadIdx.x;
    const int bb   = blockIdx.x;
    const int b    = bb >> 7;
    const int s0   = (bb & 127) << 4;
    const int wave = tid >> 6;
    const int lane = tid & 63;
    const int lq   = lane >> 4;
    const int lm   = lane & 15;
    const float* xbase = x + (size_t)b * SEQ * CH;
    const int tile0 = wave * 2;
    const int tile1 = (wave < 3) ? wave * 2 + 1 : 6;
    v4f acc0 = (v4f){0.f,0.f,0.f,0.f};
    v4f acc1 = (v4f){0.f,0.f,0.f,0.f};
    const float* arow = xbase + (size_t)(s0 + lm) * CH + lq * 8;
    #pragma unroll 8
    for (int s = 0; s < NKSTEP; ++s) {
        const float* p = arow + s * 32;
        const v4f v0 = *(const v4f*)p;
        const v4f v1 = *(const v4f*)(p + 4);
        v8bf af;
        af[0]=(__bf16)v0.x; af[1]=(__bf16)v0.y; af[2]=(__bf16)v0.z; af[3]=(__bf16)v0.w;
        af[4]=(__bf16)v1.x; af[5]=(__bf16)v1.y; af[6]=(__bf16)v1.z; af[7]=(__bf16)v1.w;
        v8bf bf0, bf1;
        #pragma unroll
        for (int j = 0; j < 8; ++j) {
            const int k = s * 32 + lq * 8 + j;
            bf0[j] = (__bf16)Wp[k * NCOL + tile0 * 16 + lm];
            bf1[j] = (__bf16)Wp[k * NCOL + tile1 * 16 + lm];
        }
        acc0 = __builtin_amdgcn_mfma_f32_16x16x32_bf16(af, bf0, acc0, 0, 0, 0);
        acc1 = __builtin_amdgcn_mfma_f32_16x16x32_bf16(af, bf1, acc1, 0, 0, 0);
    }
    {
        const int ct0 = tile0 * 16 + lm;
        const float bias0 = bp[ct0];
        #pragma unroll
        for (int r = 0; r < 4; ++r) ldsK[(lq*4+r)*113 + ct0] = acc0[r] + bias0;
        if (wave < 3) {
            const int ct1 = tile1 * 16 + lm;
            const float bias1 = bp[ct1];
            #pragma unroll
            for (int r = 0; r < 4; ++r) ldsK[(lq*4+r)*113 + ct1] = acc1[r] + bias1;
        }
    }
    const int h  = tid >> 4;
    const int c4 = tid << 2;
    v4f win[22];
    #pragma unroll
    for (int i = 0; i < 22; ++i) {
        const int sg = s0 - PADW + i;
        win[i] = (sg >= 0 && sg < SEQ) ? *(const v4f*)(xbase + (size_t)sg * CH + c4)
                                       : (v4f){0.f,0.f,0.f,0.f};
    }
    __syncthreads();
    float* orow = out + ((size_t)b * SEQ + s0) * CH + c4;
    #pragma unroll
    for (int r = 0; r < 16; ++r) {
        const float* kp = &ldsK[r * 113 + h * KSZ];
        v4f a = (v4f){0.f,0.f,0.f,0.f};
        #pragma unroll
        for (int i = 0; i < KSZ; ++i) a += kp[i] * win[r + i];
        *(v4f*)(orow + (size_t)r * CH) = a;
    }
}

extern "C" void kernel_launch(void* const* d_in, const int* in_sizes, int n_in,
                              void* d_out, int out_size, void* d_ws, size_t ws_size,
                              hipStream_t stream) {
    const float* x  = (const float*)d_in[0];
    const float* Wp = (const float*)d_in[1];
    const float* bp = (const float*)d_in[2];
    float* out = (float*)d_out;

    if (ws_size >= (size_t)WS_NEEDED) {
        __bf16* wsB  = (__bf16*)d_ws;
        float*  Kbuf = (float*)((char*)d_ws + KBUF_OFF);
        prep_w<<<dim3(448), dim3(256), 0, stream>>>(Wp, wsB);
        gemm_kernels<<<dim3(512), dim3(NTHREADS), 0, stream>>>(x, wsB, bp, Kbuf);
        dynconv<<<dim3(1024), dim3(NTHREADS), 0, stream>>>(x, Kbuf, out);
    } else {
        dynconv_fused_fb<<<dim3(512), dim3(NTHREADS), 0, stream>>>(x, Wp, bp, out);
    }
}